// Round 10
// baseline (580.696 us; speedup 1.0000x reference)
//
#include <hip/hip_runtime.h>

#define L 2048
#define CIN 16
#define GROUPS 4
#define NEG_INF  -1000000000.0f
#define POS_THRESH -100000000.0f

// ---------------------------------------------------------------------------
// Kernel A: sparsemax tau, one wave per row, FIXED-COST exact algorithm.
// (unchanged — proven)
// ---------------------------------------------------------------------------
__global__ __launch_bounds__(256) void tau_kernel(const float* __restrict__ scores,
                                                  float* __restrict__ tau_out) {
    const int wid  = (blockIdx.x << 2) + (threadIdx.x >> 6);
    const int lane = threadIdx.x & 63;
    const int ws   = threadIdx.x >> 6;            // wave slot in block
    const int ch   = wid >> 11;
    const int row  = wid & 2047;
    const int n    = row + 1;
    const float* zrow = scores + ((size_t)ch * L + row) * L;

    float v[32];
    float m = NEG_INF;
#pragma unroll
    for (int j = 0; j < 8; ++j) {
        int c4 = lane + (j << 6);
        int c  = c4 << 2;
        float4 z = make_float4(NEG_INF, NEG_INF, NEG_INF, NEG_INF);
        if (c < n) z = *((const float4*)zrow + c4);
        v[4*j+0] = (c + 0 < n) ? z.x : NEG_INF;
        v[4*j+1] = (c + 1 < n) ? z.y : NEG_INF;
        v[4*j+2] = (c + 2 < n) ? z.z : NEG_INF;
        v[4*j+3] = (c + 3 < n) ? z.w : NEG_INF;
        m = fmaxf(m, fmaxf(fmaxf(v[4*j+0], v[4*j+1]), fmaxf(v[4*j+2], v[4*j+3])));
    }
#pragma unroll
    for (int d = 32; d; d >>= 1) m = fmaxf(m, __shfl_xor(m, d, 64));

    const float thr = m - 1.0f;

    // ---- compact candidates {v > thr} into per-wave LDS buffer ----
    __shared__ float buf[4][64];
    int base = 0;
#pragma unroll
    for (int j = 0; j < 32; ++j) {
        bool p = v[j] > thr;
        unsigned long long mask = __ballot(p);
        if (mask) {
            if (p) {
                int pos = __builtin_amdgcn_mbcnt_lo((unsigned)mask, 0);
                pos = __builtin_amdgcn_mbcnt_hi((unsigned)(mask >> 32), pos);
                pos += base;
                if (pos < 64) buf[ws][pos] = v[j];
            }
            base += __popcll(mask);
        }
    }
    __syncthreads();
    const int cnt = base;

    float tau;
    if (cnt <= 64) {
        float x = (lane < cnt) ? buf[ws][lane] : NEG_INF;
        // bitonic sort, descending across 64 lanes
#pragma unroll
        for (int k = 2; k <= 64; k <<= 1) {
#pragma unroll
            for (int j = k >> 1; j > 0; j >>= 1) {
                float p = __shfl_xor(x, j, 64);
                bool desc    = ((lane & k) == 0);
                bool earlier = ((lane & j) == 0);
                float mx = fmaxf(x, p), mn = fminf(x, p);
                x = (desc == earlier) ? mx : mn;
            }
        }
        // inclusive prefix sum
        float csum = x;
#pragma unroll
        for (int d = 1; d < 64; d <<= 1) {
            float y = __shfl_up(csum, d, 64);
            if (lane >= d) csum += y;
        }
        bool cond = (1.0f + (float)(lane + 1) * x > csum) && (x > POS_THRESH);
        unsigned long long cmask = __ballot(cond);
        int k = (int)__popcll(cmask);             // k >= 1 always (max elem qualifies)
        float ck = __shfl(csum, k - 1, 64);
        tau = (ck - 1.0f) / (float)k;
    } else {
        // Michelot fallback — correctness safety net only.
        tau = thr;
        int k_prev = -1;
        for (int it = 0; it < 64; ++it) {
            float S = 0.0f, Kf = 0.0f;
#pragma unroll
            for (int j = 0; j < 32; ++j)
                if (v[j] > tau) { S += v[j]; Kf += 1.0f; }
#pragma unroll
            for (int d = 32; d; d >>= 1) {
                S  += __shfl_xor(S,  d, 64);
                Kf += __shfl_xor(Kf, d, 64);
            }
            int K = (int)Kf;
            if (K == k_prev) break;
            tau = (S - 1.0f) / Kf;
            k_prev = K;
        }
    }
    if (lane == 0) tau_out[ch * L + row] = tau;
}

// ---------------------------------------------------------------------------
// Kernel B: grouped 3x3 conv over on-the-fly probs = max(score - tau, 0).
// DIRECT-FROM-GLOBAL version: no LDS, no barriers, no ds_read.
//   Wave -> 4 output rows; lane -> (1 row x 4 cols), computes all 4 oc.
//   Each lane loads its own 3-row window per ic straight from global:
//   b128 main + b64 left (use .y) + b64 right (use .x) + tau b32.
//   Within-wave row re-reads (3x) hit L1; cross-wave/block halo re-reads hit
//   L2 (per-CU live set ~24 KB << 4 MB/XCD). Removing the staging barrier
//   lets waves free-run: r8/r9 showed HBM+VALU+DS were ~unoverlapped behind
//   __syncthreads (sum 111us ~= measured 124); DS term -> 0 here.
// Boundary tiles: per-element causal masks; halo load addresses clamped into
// the row (clamped values are always causal-masked, so never used).
// __launch_bounds__(256,4): VGPR cap 128 (r7 lesson: tighter bound = spills).
// ---------------------------------------------------------------------------
#define TR 16
#define TC 64

struct W6 { float l, m0, m1, m2, m3, r; };

__device__ __forceinline__ float rfl(float x) {
    return __builtin_bit_cast(float,
        __builtin_amdgcn_readfirstlane(__builtin_bit_cast(int, x)));
}

// interior: row in-bounds, all 6 cols causal-valid (guaranteed by tile test)
__device__ __forceinline__ W6 win_int(const float* __restrict__ rowp, float tv, int cb) {
    float4 M  = *(const float4*)(rowp + cb);
    float2 Lv = *(const float2*)(rowp + cb - 2);
    float2 Rv = *(const float2*)(rowp + cb + 4);
    W6 q;
    q.l  = fmaxf(Lv.y - tv, 0.f);
    q.m0 = fmaxf(M.x  - tv, 0.f);
    q.m1 = fmaxf(M.y  - tv, 0.f);
    q.m2 = fmaxf(M.z  - tv, 0.f);
    q.m3 = fmaxf(M.w  - tv, 0.f);
    q.r  = fmaxf(Rv.x - tv, 0.f);
    return q;
}

// checked: row guard + per-element causal mask; halo addresses clamped
// in-row (clamped elements are always masked out, never used).
__device__ __forceinline__ W6 win_chk(const float* __restrict__ sb,
                                      const float* __restrict__ tb,
                                      int r, int cb) {
    W6 q; q.l = q.m0 = q.m1 = q.m2 = q.m3 = q.r = 0.f;
    if (r >= 0 && r < L) {
        const float* rowp = sb + (size_t)r * L;
        float tv = tb[r];
        int lc = (cb >= 2) ? (cb - 2) : 0;          // 8B-aligned either way
        int rc = (cb + 4 <= L - 2) ? (cb + 4) : (L - 2);
        float4 M  = *(const float4*)(rowp + cb);
        float2 Lv = *(const float2*)(rowp + lc);
        float2 Rv = *(const float2*)(rowp + rc);
        q.l  = (cb >= 1 && cb - 1 <= r) ? fmaxf(Lv.y - tv, 0.f) : 0.f;
        q.m0 = (cb     <= r) ? fmaxf(M.x  - tv, 0.f) : 0.f;
        q.m1 = (cb + 1 <= r) ? fmaxf(M.y  - tv, 0.f) : 0.f;
        q.m2 = (cb + 2 <= r) ? fmaxf(M.z  - tv, 0.f) : 0.f;
        q.m3 = (cb + 3 <= r) ? fmaxf(M.w  - tv, 0.f) : 0.f;
        q.r  = (cb + 4 <= r) ? fmaxf(Rv.x - tv, 0.f) : 0.f;
    }
    return q;
}

__global__ __launch_bounds__(256, 4) void conv_kernel(const float* __restrict__ scores,
                                                      const float* __restrict__ tau,
                                                      const float* __restrict__ weight,
                                                      const float* __restrict__ bias,
                                                      float* __restrict__ out) {
    const int c0 = blockIdx.x * TC;
    const int r0 = blockIdx.y * TR;
    const int g  = blockIdx.z;
    const int t  = threadIdx.x;

    // Fully-dead tile: vectorized zero-fill, no loads.
    if (c0 > r0 + TR - 1) {
        const float4 z4 = make_float4(0.f, 0.f, 0.f, 0.f);
#pragma unroll
        for (int jj = 0; jj < 4; ++jj) {
            int idx = t + (jj << 8);              // 0..1023
            int c4  = idx & 15;
            int r   = (idx >> 4) & 15;
            int o   = idx >> 8;
            float4* p = (float4*)(out + (((size_t)((g << 2) + o) * L + (r0 + r)) * L + c0)) + c4;
            *p = z4;
        }
        return;
    }

    const bool interior = (c0 >= 1) && (c0 + TC + 1 <= r0) && (r0 + TR <= L - 1);

    const float* sbase = scores + (size_t)(g << 2) * L * L;
    const float* tbase = tau + (g << 2) * L;

    const int w4   = t >> 6;
    const int lane = t & 63;
    const int col4 = lane & 15;
    const int rloc = lane >> 4;
    const int ro   = (w4 << 2) + rloc;             // output row within tile 0..15
    const int r_out = r0 + ro;                     // 0..2047 always
    const int obase = g << 2;
    const int cb   = c0 + (col4 << 2);

    float4 acc[4];
#pragma unroll
    for (int oc = 0; oc < 4; ++oc) {
        float bb = rfl(bias[obase + oc]);
        acc[oc] = make_float4(bb, bb, bb, bb);
    }

#define ROWFMA(q, wa, wb, wc, A)                                           \
    A.x = fmaf(q.l,  wa, fmaf(q.m0, wb, fmaf(q.m1, wc, A.x)));             \
    A.y = fmaf(q.m0, wa, fmaf(q.m1, wb, fmaf(q.m2, wc, A.y)));             \
    A.z = fmaf(q.m1, wa, fmaf(q.m2, wb, fmaf(q.m3, wc, A.z)));             \
    A.w = fmaf(q.m2, wa, fmaf(q.m3, wb, fmaf(q.r,  wc, A.w)));

#define OCLOOP(ic, Q0, Q1, Q2)                                             \
    _Pragma("unroll")                                                      \
    for (int oc = 0; oc < 4; ++oc) {                                       \
        const float* wp = weight + (((obase + oc) << 2) + (ic)) * 9;       \
        const float w00 = rfl(wp[0]), w01 = rfl(wp[1]), w02 = rfl(wp[2]);  \
        const float w10 = rfl(wp[3]), w11 = rfl(wp[4]), w12 = rfl(wp[5]);  \
        const float w20 = rfl(wp[6]), w21 = rfl(wp[7]), w22 = rfl(wp[8]);  \
        ROWFMA(Q0, w00, w01, w02, acc[oc])                                 \
        ROWFMA(Q1, w10, w11, w12, acc[oc])                                 \
        ROWFMA(Q2, w20, w21, w22, acc[oc])                                 \
    }

    if (interior) {
        // rows r_out-1 .. r_out+1 all in-bounds & causal-valid for cols
        // cb-1 .. cb+4 (c0>=64, c0+65<=r0, r0+16<=2047).
#pragma unroll
        for (int ic = 0; ic < 4; ++ic) {
            const float* sb = sbase + (size_t)ic * L * L;
            const float* tb = tbase + ic * L;
            const float* rp = sb + (size_t)(r_out - 1) * L;
            W6 q0 = win_int(rp,           tb[r_out - 1], cb);
            W6 q1 = win_int(rp + L,       tb[r_out],     cb);
            W6 q2 = win_int(rp + 2 * L,   tb[r_out + 1], cb);
            OCLOOP(ic, q0, q1, q2)
        }
    } else {
#pragma unroll
        for (int ic = 0; ic < 4; ++ic) {
            const float* sb = sbase + (size_t)ic * L * L;
            const float* tb = tbase + ic * L;
            W6 q0 = win_chk(sb, tb, r_out - 1, cb);
            W6 q1 = win_chk(sb, tb, r_out,     cb);
            W6 q2 = win_chk(sb, tb, r_out + 1, cb);
            OCLOOP(ic, q0, q1, q2)
        }
    }
#undef OCLOOP
#undef ROWFMA

    if (interior) {
#pragma unroll
        for (int oc = 0; oc < 4; ++oc) {
            float* outp = out + ((size_t)(obase + oc) * L + r_out) * L + cb;
            *(float4*)outp = acc[oc];
        }
    } else {
#pragma unroll
        for (int oc = 0; oc < 4; ++oc) {
            float4 res;
            res.x = (cb     <= r_out) ? acc[oc].x : 0.f;
            res.y = (cb + 1 <= r_out) ? acc[oc].y : 0.f;
            res.z = (cb + 2 <= r_out) ? acc[oc].z : 0.f;
            res.w = (cb + 3 <= r_out) ? acc[oc].w : 0.f;
            float* outp = out + ((size_t)(obase + oc) * L + r_out) * L + cb;
            *(float4*)outp = res;
        }
    }
}

extern "C" void kernel_launch(void* const* d_in, const int* in_sizes, int n_in,
                              void* d_out, int out_size, void* d_ws, size_t ws_size,
                              hipStream_t stream) {
    const float* scores = (const float*)d_in[0];
    const float* weight = (const float*)d_in[1];
    const float* bias   = (const float*)d_in[2];
    float* out = (float*)d_out;
    float* tau = (float*)d_ws;                 // 16*2048 floats = 128 KB

    tau_kernel<<<(CIN * L) / 4, 256, 0, stream>>>(scores, tau);

    dim3 gridB(L / TC, L / TR, GROUPS);
    conv_kernel<<<gridB, 256, 0, stream>>>(scores, tau, weight, bias, out);
}

// Round 11
// 494.250 us; speedup vs baseline: 1.1749x; 1.1749x over previous
//
#include <hip/hip_runtime.h>

#define L 2048
#define CIN 16
#define GROUPS 4
#define NEG_INF  -1000000000.0f
#define POS_THRESH -100000000.0f

// ---------------------------------------------------------------------------
// Kernel A: sparsemax tau, one wave per row, FIXED-COST exact algorithm.
// (unchanged — proven)
// ---------------------------------------------------------------------------
__global__ __launch_bounds__(256) void tau_kernel(const float* __restrict__ scores,
                                                  float* __restrict__ tau_out) {
    const int wid  = (blockIdx.x << 2) + (threadIdx.x >> 6);
    const int lane = threadIdx.x & 63;
    const int ws   = threadIdx.x >> 6;            // wave slot in block
    const int ch   = wid >> 11;
    const int row  = wid & 2047;
    const int n    = row + 1;
    const float* zrow = scores + ((size_t)ch * L + row) * L;

    float v[32];
    float m = NEG_INF;
#pragma unroll
    for (int j = 0; j < 8; ++j) {
        int c4 = lane + (j << 6);
        int c  = c4 << 2;
        float4 z = make_float4(NEG_INF, NEG_INF, NEG_INF, NEG_INF);
        if (c < n) z = *((const float4*)zrow + c4);
        v[4*j+0] = (c + 0 < n) ? z.x : NEG_INF;
        v[4*j+1] = (c + 1 < n) ? z.y : NEG_INF;
        v[4*j+2] = (c + 2 < n) ? z.z : NEG_INF;
        v[4*j+3] = (c + 3 < n) ? z.w : NEG_INF;
        m = fmaxf(m, fmaxf(fmaxf(v[4*j+0], v[4*j+1]), fmaxf(v[4*j+2], v[4*j+3])));
    }
#pragma unroll
    for (int d = 32; d; d >>= 1) m = fmaxf(m, __shfl_xor(m, d, 64));

    const float thr = m - 1.0f;

    // ---- compact candidates {v > thr} into per-wave LDS buffer ----
    __shared__ float buf[4][64];
    int base = 0;
#pragma unroll
    for (int j = 0; j < 32; ++j) {
        bool p = v[j] > thr;
        unsigned long long mask = __ballot(p);
        if (mask) {
            if (p) {
                int pos = __builtin_amdgcn_mbcnt_lo((unsigned)mask, 0);
                pos = __builtin_amdgcn_mbcnt_hi((unsigned)(mask >> 32), pos);
                pos += base;
                if (pos < 64) buf[ws][pos] = v[j];
            }
            base += __popcll(mask);
        }
    }
    __syncthreads();
    const int cnt = base;

    float tau;
    if (cnt <= 64) {
        float x = (lane < cnt) ? buf[ws][lane] : NEG_INF;
        // bitonic sort, descending across 64 lanes
#pragma unroll
        for (int k = 2; k <= 64; k <<= 1) {
#pragma unroll
            for (int j = k >> 1; j > 0; j >>= 1) {
                float p = __shfl_xor(x, j, 64);
                bool desc    = ((lane & k) == 0);
                bool earlier = ((lane & j) == 0);
                float mx = fmaxf(x, p), mn = fminf(x, p);
                x = (desc == earlier) ? mx : mn;
            }
        }
        // inclusive prefix sum
        float csum = x;
#pragma unroll
        for (int d = 1; d < 64; d <<= 1) {
            float y = __shfl_up(csum, d, 64);
            if (lane >= d) csum += y;
        }
        bool cond = (1.0f + (float)(lane + 1) * x > csum) && (x > POS_THRESH);
        unsigned long long cmask = __ballot(cond);
        int k = (int)__popcll(cmask);             // k >= 1 always (max elem qualifies)
        float ck = __shfl(csum, k - 1, 64);
        tau = (ck - 1.0f) / (float)k;
    } else {
        // Michelot fallback — correctness safety net only.
        tau = thr;
        int k_prev = -1;
        for (int it = 0; it < 64; ++it) {
            float S = 0.0f, Kf = 0.0f;
#pragma unroll
            for (int j = 0; j < 32; ++j)
                if (v[j] > tau) { S += v[j]; Kf += 1.0f; }
#pragma unroll
            for (int d = 32; d; d >>= 1) {
                S  += __shfl_xor(S,  d, 64);
                Kf += __shfl_xor(Kf, d, 64);
            }
            int K = (int)Kf;
            if (K == k_prev) break;
            tau = (S - 1.0f) / Kf;
            k_prev = K;
        }
    }
    if (lane == 0) tau_out[ch * L + row] = tau;
}

// ---------------------------------------------------------------------------
// Kernel B: grouped 3x3 conv over on-the-fly probs = max(score - tau, 0).
// r8 structure (LDS staging, wave->4-output-rows compute, rfl weights,
// __launch_bounds__(256,4)) with a 2-PHASE / 2-IC PIPELINE:
//   load(ic0,ic1)->regs; ds_write; ISSUE load(ic2,ic3); barrier;
//   compute(ic0,ic1); ds_write(ic2,ic3); barrier; compute(ic2,ic3).
// Per-phase compute (~1600 cy) >> HBM latency (~900 cy) so the ic23 loads
// fly under compute01 (r9's failure: 1-ic phases = 400 cy < latency, and 4
// barriers). Same 19.6 KB LDS (2 bufs x 2 ic) -> 8 blocks/CU; 2 barriers.
// ---------------------------------------------------------------------------
#define TR 16
#define TC 64
#define HR 18
#define PST 68

struct W6 { float l, m0, m1, m2, m3, r; };
struct Stage { float4 z0, z1; float tv0, tv1, hv; };

__device__ __forceinline__ float rfl(float x) {
    return __builtin_bit_cast(float,
        __builtin_amdgcn_readfirstlane(__builtin_bit_cast(int, x)));
}

template<bool CHK>
__device__ __forceinline__ void load_stage(Stage& s, const float* __restrict__ sb,
                                           const float* __restrict__ tb,
                                           int r0, int c0, int t) {
    const int hr = t >> 4, c4 = t & 15;
    const int r  = r0 - 1 + hr;
    const int cb = c0 + (c4 << 2);
    if (!CHK) {
        s.z0  = *((const float4*)(sb + (size_t)r * L + c0) + c4);
        s.tv0 = tb[r];
    } else {
        s.z0 = make_float4(0.f, 0.f, 0.f, 0.f); s.tv0 = 0.f;
        if (r >= 0 && r < L && cb <= r) {
            s.z0  = *((const float4*)(sb + (size_t)r * L) + (cb >> 2));
            s.tv0 = tb[r];
            if (cb + 1 > r) s.z0.y = s.tv0;
            if (cb + 2 > r) s.z0.z = s.tv0;
            if (cb + 3 > r) s.z0.w = s.tv0;
        }
    }
    if (t < 32) {
        const int r1 = r0 + 15 + (t >> 4);        // rows 16,17 of the stage
        if (!CHK) {
            s.z1  = *((const float4*)(sb + (size_t)r1 * L + c0) + c4);
            s.tv1 = tb[r1];
        } else {
            s.z1 = make_float4(0.f, 0.f, 0.f, 0.f); s.tv1 = 0.f;
            if (r1 >= 0 && r1 < L && cb <= r1) {
                s.z1  = *((const float4*)(sb + (size_t)r1 * L) + (cb >> 2));
                s.tv1 = tb[r1];
                if (cb + 1 > r1) s.z1.y = s.tv1;
                if (cb + 2 > r1) s.z1.z = s.tv1;
                if (cb + 3 > r1) s.z1.w = s.tv1;
            }
        }
    }
    if (t >= 64 && t < 100) {
        const int j = t - 64, side = j & 1, hhr = j >> 1;
        const int r2 = r0 - 1 + hhr;
        const int c  = side ? (c0 + TC) : (c0 - 1);
        if (!CHK) {
            s.hv = fmaxf(sb[(size_t)r2 * L + c] - tb[r2], 0.f);
        } else {
            s.hv = 0.f;
            if (r2 >= 0 && r2 < L && c >= 0 && c <= r2)
                s.hv = fmaxf(sb[(size_t)r2 * L + c] - tb[r2], 0.f);
        }
    }
}

__device__ __forceinline__ void store_stage(const Stage& s, float B[HR][PST], int t) {
    const int hr = t >> 4, c4 = t & 15;
    float4 v;
    v.x = fmaxf(s.z0.x - s.tv0, 0.f);
    v.y = fmaxf(s.z0.y - s.tv0, 0.f);
    v.z = fmaxf(s.z0.z - s.tv0, 0.f);
    v.w = fmaxf(s.z0.w - s.tv0, 0.f);
    *((float4*)&B[hr][c4 << 2]) = v;
    if (t < 32) {
        const int hr1 = 16 + (t >> 4);
        float4 u;
        u.x = fmaxf(s.z1.x - s.tv1, 0.f);
        u.y = fmaxf(s.z1.y - s.tv1, 0.f);
        u.z = fmaxf(s.z1.z - s.tv1, 0.f);
        u.w = fmaxf(s.z1.w - s.tv1, 0.f);
        *((float4*)&B[hr1][c4 << 2]) = u;
    }
    if (t >= 64 && t < 100) {
        const int j = t - 64, side = j & 1, hhr = j >> 1;
        B[hhr][side ? TC : 67] = s.hv;
    }
}

__global__ __launch_bounds__(256, 4) void conv_kernel(const float* __restrict__ scores,
                                                      const float* __restrict__ tau,
                                                      const float* __restrict__ weight,
                                                      const float* __restrict__ bias,
                                                      float* __restrict__ out) {
    const int c0 = blockIdx.x * TC;
    const int r0 = blockIdx.y * TR;
    const int g  = blockIdx.z;
    const int t  = threadIdx.x;

    // Fully-dead tile: vectorized zero-fill, no loads.
    if (c0 > r0 + TR - 1) {
        const float4 z4 = make_float4(0.f, 0.f, 0.f, 0.f);
#pragma unroll
        for (int jj = 0; jj < 4; ++jj) {
            int idx = t + (jj << 8);              // 0..1023
            int c4  = idx & 15;
            int r   = (idx >> 4) & 15;
            int o   = idx >> 8;
            float4* p = (float4*)(out + (((size_t)((g << 2) + o) * L + (r0 + r)) * L + c0)) + c4;
            *p = z4;
        }
        return;
    }

    __shared__ __align__(16) float Pb[2][2][HR][PST];   // 19,584 B (= r8)

    const bool interior = (c0 >= 1) && (c0 + TC + 1 <= r0) && (r0 + TR <= L - 1);

    const float* sbase = scores + (size_t)(g << 2) * L * L;
    const float* tbase = tau + (g << 2) * L;

    // ---- compute-geometry (wave = 4 output rows) ----
    const int w4   = t >> 6;
    const int lane = t & 63;
    const int col4 = lane & 15;
    const int rloc = lane >> 4;
    const int ro   = (w4 << 2) + rloc;             // output row within tile 0..15
    const int obase = g << 2;
    const int cb   = c0 + (col4 << 2);
    const int li   = col4 ? ((col4 << 2) - 2) : 66;   // left b64 idx (use .y)
    const int ri   = (col4 << 2) + 4;                 // right b64 idx (use .x)

    auto ldwin = [&](const float (*B)[PST], int hr) -> W6 {
        const float* rp = &B[hr][0];
        float4 M  = *(const float4*)(rp + (col4 << 2));
        float2 Lv = *(const float2*)(rp + li);
        float2 Rv = *(const float2*)(rp + ri);
        W6 q; q.l = Lv.y; q.m0 = M.x; q.m1 = M.y; q.m2 = M.z; q.m3 = M.w; q.r = Rv.x;
        return q;
    };

    float4 acc[4];
#pragma unroll
    for (int oc = 0; oc < 4; ++oc) {
        float bb = rfl(bias[obase + oc]);
        acc[oc] = make_float4(bb, bb, bb, bb);
    }

#define ROWFMA(q, wa, wb, wc, A)                                           \
    A.x = fmaf(q.l,  wa, fmaf(q.m0, wb, fmaf(q.m1, wc, A.x)));             \
    A.y = fmaf(q.m0, wa, fmaf(q.m1, wb, fmaf(q.m2, wc, A.y)));             \
    A.z = fmaf(q.m1, wa, fmaf(q.m2, wb, fmaf(q.m3, wc, A.z)));             \
    A.w = fmaf(q.m2, wa, fmaf(q.m3, wb, fmaf(q.r,  wc, A.w)));

#define COMPUTE_IC(ic, BUF)                                                \
    {                                                                      \
        W6 q0 = ldwin(BUF, ro);                                            \
        W6 q1 = ldwin(BUF, ro + 1);                                        \
        W6 q2 = ldwin(BUF, ro + 2);                                        \
        _Pragma("unroll")                                                  \
        for (int oc = 0; oc < 4; ++oc) {                                   \
            const float* wp = weight + (((obase + oc) << 2) + (ic)) * 9;   \
            const float w00 = rfl(wp[0]), w01 = rfl(wp[1]), w02 = rfl(wp[2]); \
            const float w10 = rfl(wp[3]), w11 = rfl(wp[4]), w12 = rfl(wp[5]); \
            const float w20 = rfl(wp[6]), w21 = rfl(wp[7]), w22 = rfl(wp[8]); \
            ROWFMA(q0, w00, w01, w02, acc[oc])                             \
            ROWFMA(q1, w10, w11, w12, acc[oc])                             \
            ROWFMA(q2, w20, w21, w22, acc[oc])                             \
        }                                                                  \
    }

#define PIPELINE(CHKV)                                                     \
    {                                                                      \
        Stage s0, s1, s2, s3;                                              \
        load_stage<CHKV>(s0, sbase,                  tbase,         r0, c0, t); \
        load_stage<CHKV>(s1, sbase + (size_t)L * L,  tbase + L,     r0, c0, t); \
        store_stage(s0, Pb[0][0], t);                                      \
        store_stage(s1, Pb[0][1], t);                                      \
        /* issue phase-2 loads BEFORE the barrier: in flight under compute01 */ \
        load_stage<CHKV>(s2, sbase + (size_t)2 * L * L, tbase + 2 * L, r0, c0, t); \
        load_stage<CHKV>(s3, sbase + (size_t)3 * L * L, tbase + 3 * L, r0, c0, t); \
        __syncthreads();                                                   \
        COMPUTE_IC(0, Pb[0][0])                                            \
        COMPUTE_IC(1, Pb[0][1])                                            \
        store_stage(s2, Pb[1][0], t);                                      \
        store_stage(s3, Pb[1][1], t);                                      \
        __syncthreads();                                                   \
        COMPUTE_IC(2, Pb[1][0])                                            \
        COMPUTE_IC(3, Pb[1][1])                                            \
    }

    if (interior) {
        PIPELINE(false)
    } else {
        PIPELINE(true)
    }
#undef PIPELINE
#undef COMPUTE_IC
#undef ROWFMA

    const int r_out = r0 + ro;
    if (interior) {
#pragma unroll
        for (int oc = 0; oc < 4; ++oc) {
            float* outp = out + ((size_t)(obase + oc) * L + r_out) * L + cb;
            *(float4*)outp = acc[oc];
        }
    } else {
#pragma unroll
        for (int oc = 0; oc < 4; ++oc) {
            float4 res;
            res.x = (cb     <= r_out) ? acc[oc].x : 0.f;
            res.y = (cb + 1 <= r_out) ? acc[oc].y : 0.f;
            res.z = (cb + 2 <= r_out) ? acc[oc].z : 0.f;
            res.w = (cb + 3 <= r_out) ? acc[oc].w : 0.f;
            float* outp = out + ((size_t)(obase + oc) * L + r_out) * L + cb;
            *(float4*)outp = res;
        }
    }
}

extern "C" void kernel_launch(void* const* d_in, const int* in_sizes, int n_in,
                              void* d_out, int out_size, void* d_ws, size_t ws_size,
                              hipStream_t stream) {
    const float* scores = (const float*)d_in[0];
    const float* weight = (const float*)d_in[1];
    const float* bias   = (const float*)d_in[2];
    float* out = (float*)d_out;
    float* tau = (float*)d_ws;                 // 16*2048 floats = 128 KB

    tau_kernel<<<(CIN * L) / 4, 256, 0, stream>>>(scores, tau);

    dim3 gridB(L / TC, L / TR, GROUPS);
    conv_kernel<<<gridB, 256, 0, stream>>>(scores, tau, weight, bias, out);
}